// Round 5
// baseline (33.168 us; speedup 1.0000x reference)
//
#include <hip/hip_runtime.h>
#include <hip/hip_bf16.h>
#include <stdint.h>

// Problem constants (from reference)
#define IN_F   4096
#define OUT_F  4096
#define NGRP   32
#define NBLK   32
#define GSZ    128
#define OFI    128
#define WPB    1536          // int32 words per (group, out-block)
#define M_TOK  128
#define KSPLIT 8
#define NTILE  64            // columns per GEMM block

typedef __attribute__((ext_vector_type(8))) short bf16x8;
typedef __attribute__((ext_vector_type(4))) float f32x4;

// one-instruction packed f32x2 -> bf16x2 (RNE), gfx950
static __device__ __forceinline__ unsigned cvt_pk_bf16(float lo, float hi) {
    unsigned r;
    asm("v_cvt_pk_bf16_f32 %0, %1, %2" : "=v"(r) : "v"(lo), "v"(hi));
    return r;
}

// async global->LDS, 16B per lane; LDS dest must be wave-uniform base (+lane*16)
static __device__ __forceinline__ void gload_lds16(const void* g, void* s) {
    __builtin_amdgcn_global_load_lds(
        (const __attribute__((address_space(1))) unsigned int*)g,
        (__attribute__((address_space(3))) unsigned int*)s, 16, 0, 0);
}

// ---------------------------------------------------------------------------
// Prep kernel (3 roles by blockIdx.x):
//   [0,256):    xr[t][i] = bf16(x[t][in_reorder[i]])  8 gathers/thread
//   [256,260):  inv_out[out_reorder[i]] = i
//   [260,388):  A2 = 2*alpha ; B7 = beta - 7*alpha
// ---------------------------------------------------------------------------
__global__ __launch_bounds__(256) void k_prep(const float* __restrict__ x,
                                              const int* __restrict__ in_reorder,
                                              const int* __restrict__ out_reorder,
                                              const float* __restrict__ alpha,
                                              const float* __restrict__ beta,
                                              unsigned short* __restrict__ xr,
                                              int* __restrict__ inv_out,
                                              float* __restrict__ A2,
                                              float* __restrict__ B7) {
    int b = blockIdx.x;
    if (b < 256) {
        int idx = b * 256 + threadIdx.x;          // 0..65535, 8 elems each
        int t  = idx >> 9;
        int i0 = (idx & 511) << 3;
        int4 s0 = *(const int4*)&in_reorder[i0];
        int4 s1 = *(const int4*)&in_reorder[i0 + 4];
        const float* row = x + (size_t)t * IN_F;
        float v0 = row[s0.x], v1 = row[s0.y], v2 = row[s0.z], v3 = row[s0.w];
        float v4 = row[s1.x], v5 = row[s1.y], v6 = row[s1.z], v7 = row[s1.w];
        uint4 pk;
        pk.x = cvt_pk_bf16(v0, v1);
        pk.y = cvt_pk_bf16(v2, v3);
        pk.z = cvt_pk_bf16(v4, v5);
        pk.w = cvt_pk_bf16(v6, v7);
        *(uint4*)&xr[(size_t)t * IN_F + i0] = pk;
    } else if (b < 260) {
        int i0 = ((b - 256) * 256 + threadIdx.x) << 2;   // 0..4095 step 4
        int4 o = *(const int4*)&out_reorder[i0];
        inv_out[o.x] = i0;
        inv_out[o.y] = i0 + 1;
        inv_out[o.z] = i0 + 2;
        inv_out[o.w] = i0 + 3;
    } else {
        int idx = ((b - 260) * 256 + threadIdx.x) << 2;  // 0..131068 step 4
        float4 a = *(const float4*)&alpha[idx];
        float4 bt = *(const float4*)&beta[idx];
        float4 a2 = make_float4(2.f * a.x, 2.f * a.y, 2.f * a.z, 2.f * a.w);
        float4 b7 = make_float4(bt.x - 7.f * a.x, bt.y - 7.f * a.y,
                                bt.z - 7.f * a.z, bt.w - 7.f * a.w);
        *(float4*)&A2[idx] = a2;
        *(float4*)&B7[idx] = b7;
    }
}

// ---------------------------------------------------------------------------
// Fused dequant + split-K bf16 MFMA GEMM.
//   Cpart[ks][t][c] = sum_{k in ks-chunk} xr[t][k] * W[k][c]
// Block: 256 threads (4 waves as 2m x 2n), tile 128 x 64, BK=128 (one quant
// group per K-step), grid (64 nb, 8 ks) = 512 blocks -> 2 blocks/CU.
// A-tile staged with global_load_lds + pre-swizzled per-lane global address
// (LDS stays linear; the swizzle lives in the source address). B-tile is
// dequantized in registers and ds_written swizzled. Swizzle (both tiles):
//   elem(row,k) = row*128 + (((k>>3) ^ (row&15))<<3) + (k&7)
// ---------------------------------------------------------------------------
__global__ __launch_bounds__(256, 2) void k_fused(const unsigned short* __restrict__ xr,
                                                  const int* __restrict__ qweight,
                                                  const float* __restrict__ A2,
                                                  const float* __restrict__ B7,
                                                  const int* __restrict__ offset,
                                                  float* __restrict__ Cpart) {
    __shared__ unsigned short Alds[128 * 128];   // 32 KB, linear dest for gload_lds
    __shared__ unsigned short Blds[NTILE * 128]; // 16 KB
    const int nb  = blockIdx.x;            // 0..63
    const int ks  = blockIdx.y;            // 0..7
    const int n   = nb >> 1;               // 128-col out-block
    const int wcb = (nb & 1) * 2;          // word-quarter base (0 or 2)
    const int n0  = nb * NTILE;            // global col base
    const int tid = threadIdx.x;
    const int l   = tid & 63;
    const int wid = tid >> 6;              // 0..3
    const int wm  = wid >> 1;              // row half
    const int wn  = wid & 1;               // col half

    // dequant role: io-pair p, word-quarter wc (0/1 within our 64 cols), col-half h
    const int p  = tid >> 2;               // 0..63  -> io = 2p, 2p+1
    const int wc = (tid >> 1) & 1;
    const int h  = tid & 1;
    const int wq = wcb + wc;               // word quarter 0..3
    const int io0 = 2 * p;

    // A-stage lane geometry: call i covers rows wid*32+i*4 .. +4
    const int rl = l >> 4;                 // row-in-call
    const int cl = l & 15;                 // 16B col slot

    f32x4 acc[4][2] = {};

    // prefetch K-tile 0's qweight words (synchronous-ish; only once)
    int cw0a, cw0b, cw1a, cw1b, cw2a, cw2b;
    {
        const int gb0 = (ks * 4) * NBLK + n;
        const int* q = qweight + offset[gb0];
        cw0a = q[ io0      * 4 + wq];
        cw0b = q[(io0 + 1) * 4 + wq];
        cw1a = q[ io0      * 4 + wq + 512];
        cw1b = q[(io0 + 1) * 4 + wq + 512];
        cw2a = q[ io0      * 4 + wq + 1024];
        cw2b = q[(io0 + 1) * 4 + wq + 1024];
    }

    #pragma unroll
    for (int kt = 0; kt < 4; ++kt) {
        const int g  = ks * 4 + kt;        // quant group
        const int k0 = g * GSZ;

        // ---- stage A: 8 async 1KB chunks per wave, source pre-swizzled ----
        #pragma unroll
        for (int i = 0; i < 8; ++i) {
            int R = wid * 32 + i * 4 + rl;
            const unsigned short* src = xr + ((size_t)R << 12) + k0 + ((cl ^ (R & 15)) << 3);
            gload_lds16(src, (char*)Alds + wid * 8192 + i * 1024);
        }

        // ---- dequant B: 64 cols x 128 io -> swizzled LDS ----
        {
            const float* a2 = A2 + g * OUT_F + n0 + wc * 32 + h * 16;
            const float* b7 = B7 + g * OUT_F + n0 + wc * 32 + h * 16;
            unsigned* B32 = (unsigned*)Blds;
            #pragma unroll
            for (int j = 0; j < 16; ++j) {
                int jb  = h * 16 + j;              // bit index in word
                int col = wc * 32 + jb;            // local col 0..63
                float sa = a2[j];
                float sb = b7[j];
                int na  = ((cw0a >> jb) & 1) | (((cw1a >> jb) & 1) << 1) | (((cw2a >> jb) & 1) << 2);
                int nbq = ((cw0b >> jb) & 1) | (((cw1b >> jb) & 1) << 1) | (((cw2b >> jb) & 1) << 2);
                float va = (float)na  * sa + sb;
                float vb = (float)nbq * sa + sb;
                B32[col * 64 + (((p >> 2) ^ (col & 15)) << 2) + (p & 3)] = cvt_pk_bf16(va, vb);
            }
        }
        __syncthreads();   // drains A-loads (vmcnt) + B ds_writes (lgkmcnt)

        // ---- prefetch next K-tile's words: overlaps with MFMA below ----
        if (kt < 3) {
            const int gb1 = (ks * 4 + kt + 1) * NBLK + n;
            const int* q = qweight + offset[gb1];
            cw0a = q[ io0      * 4 + wq];
            cw0b = q[(io0 + 1) * 4 + wq];
            cw1a = q[ io0      * 4 + wq + 512];
            cw1b = q[(io0 + 1) * 4 + wq + 512];
            cw2a = q[ io0      * 4 + wq + 1024];
            cw2b = q[(io0 + 1) * 4 + wq + 1024];
        }

        // ---- MFMA over the 128-K tile ----
        __builtin_amdgcn_s_setprio(1);
        #pragma unroll
        for (int kk = 0; kk < 4; ++kk) {
            const int cb = kk * 4 + (l >> 4);
            bf16x8 af[4], bfr[2];
            #pragma unroll
            for (int m = 0; m < 4; ++m) {
                int row = wm * 64 + m * 16 + (l & 15);
                af[m] = *(const bf16x8*)&Alds[row * 128 + ((cb ^ (row & 15)) << 3)];
            }
            #pragma unroll
            for (int nn = 0; nn < 2; ++nn) {
                int clr = wn * 32 + nn * 16 + (l & 15);
                bfr[nn] = *(const bf16x8*)&Blds[clr * 128 + ((cb ^ (clr & 15)) << 3)];
            }
            #pragma unroll
            for (int m = 0; m < 4; ++m)
                #pragma unroll
                for (int nn = 0; nn < 2; ++nn)
                    acc[m][nn] = __builtin_amdgcn_mfma_f32_16x16x32_bf16(
                        af[m], bfr[nn], acc[m][nn], 0, 0, 0);
        }
        __builtin_amdgcn_s_setprio(0);
        __syncthreads();
    }

    // ---- epilogue: per-wave 64x32 tile -> Cpart[ks] ----
    float* Cb = Cpart + (size_t)ks * (M_TOK * OUT_F);
    #pragma unroll
    for (int m = 0; m < 4; ++m) {
        int row = wm * 64 + m * 16 + ((l >> 4) << 2);
        #pragma unroll
        for (int nn = 0; nn < 2; ++nn) {
            int col = n0 + wn * 32 + nn * 16 + (l & 15);
            #pragma unroll
            for (int r = 0; r < 4; ++r)
                Cb[(size_t)(row + r) * OUT_F + col] = acc[m][nn][r];
        }
    }
}

// ---------------------------------------------------------------------------
// Reduce: out[t][inv_out[c]] = sum_ks Cpart[ks][t][c]
//   coalesced float4 reads, scattered 4B writes (L2 merges lines).
// ---------------------------------------------------------------------------
__global__ __launch_bounds__(256) void k_reduce(const float* __restrict__ Cpart,
                                                const int* __restrict__ inv_out,
                                                float* __restrict__ out) {
    int idx = blockIdx.x * 256 + threadIdx.x;   // 0..131071, 4 cols each
    int t  = idx >> 10;
    int c0 = (idx & 1023) << 2;
    float4 s = make_float4(0.f, 0.f, 0.f, 0.f);
    #pragma unroll
    for (int ks = 0; ks < KSPLIT; ++ks) {
        float4 v = *(const float4*)&Cpart[(size_t)ks * (M_TOK * OUT_F) + (size_t)t * OUT_F + c0];
        s.x += v.x; s.y += v.y; s.z += v.z; s.w += v.w;
    }
    const int* op = &inv_out[c0];
    float* row = out + (size_t)t * OUT_F;
    row[op[0]] = s.x;
    row[op[1]] = s.y;
    row[op[2]] = s.z;
    row[op[3]] = s.w;
}

// ---------------------------------------------------------------------------
extern "C" void kernel_launch(void* const* d_in, const int* in_sizes, int n_in,
                              void* d_out, int out_size, void* d_ws, size_t ws_size,
                              hipStream_t stream) {
    const float* x           = (const float*)d_in[0];
    const int*   qweight     = (const int*)d_in[1];
    const float* alpha       = (const float*)d_in[2];
    const float* beta        = (const float*)d_in[3];
    // d_in[4] = block_bitwidth (uniform 3, unused)
    const int*   offset      = (const int*)d_in[5];
    const int*   in_reorder  = (const int*)d_in[6];
    const int*   out_reorder = (const int*)d_in[7];
    float* out = (float*)d_out;

    // workspace: xr (1MB) | Cpart (16MB) | inv_out (16KB) | A2 (512KB) | B7 (512KB)
    char* ws = (char*)d_ws;
    unsigned short* xr      = (unsigned short*)ws;
    float*          Cpart   = (float*)(ws + (1u << 20));
    int*            inv_out = (int*)(ws + (1u << 20) + (16u << 20));
    float*          A2      = (float*)(ws + (1u << 20) + (16u << 20) + (16u << 10));
    float*          B7      = A2 + NGRP * OUT_F;

    k_prep<<<dim3(388), dim3(256), 0, stream>>>(x, in_reorder, out_reorder,
                                                alpha, beta, xr, inv_out, A2, B7);
    k_fused<<<dim3(64, KSPLIT), dim3(256), 0, stream>>>(xr, qweight, A2, B7, offset, Cpart);
    k_reduce<<<dim3(512), dim3(256), 0, stream>>>(Cpart, inv_out, out);
}